// Round 2
// baseline (1042.520 us; speedup 1.0000x reference)
//
#include <hip/hip_runtime.h>
#include <hip/hip_bf16.h>

#define N_S 1024
#define N_R 768
#define LN_EPS 1e-5f
#define MEAN_EPS 1e-10f
#define LARGE_F 1e9f
#define QSCALE 0.35355339059327373f  // 8^-0.5

__device__ __forceinline__ float bflo(unsigned u){ union{unsigned v; float f;} x; x.v = u << 16; return x.f; }
__device__ __forceinline__ float bfhi(unsigned u){ union{unsigned v; float f;} x; x.v = u & 0xffff0000u; return x.f; }
__device__ __forceinline__ unsigned short f2b(float f){
  __hip_bfloat16 h = __float2bfloat16(f);
  return *reinterpret_cast<unsigned short*>(&h);
}

// LDS: k/v cache (fp16) unioned with per-thread staging rows (packed bf16 pairs)
union SharedU {
  _Float16 kv[N_S][16];      // [s][0..7]=k, [s][8..15]=v   (32 KiB)
  unsigned stage[256][33];   // 33 words/row (64 shorts + pad) (33 KiB)
};

__global__ __launch_bounds__(256, 2) void attn_kernel(
    const float* __restrict__ act, const float* __restrict__ mask,
    const float* __restrict__ lns, const float* __restrict__ lnb,
    const float* __restrict__ qw,  const float* __restrict__ kw,
    const float* __restrict__ vw,  const float* __restrict__ gw,
    const float* __restrict__ gb,  const float* __restrict__ ow,
    const float* __restrict__ ob,  float* __restrict__ out)
{
  __shared__ SharedU sh;
  __shared__ float redA[4][64];
  __shared__ float redB[4][8];
  __shared__ float q_lds[64];
  __shared__ float qf_lds[64];
  __shared__ float wavg_lds[64];

  const int tid  = threadIdx.x;
  const int lane = tid & 63;
  const int wave = tid >> 6;
  const int r    = blockIdx.x;

  // ================= pass 1: LN + k/v projections + masked q-sum =================
  float qacc[64];
  #pragma unroll
  for (int c = 0; c < 64; c++) qacc[c] = 0.f;
  float msum = 0.f;

  #pragma unroll 1
  for (int it = 0; it < 4; it++) {
    int s = tid + it * 256;
    size_t base = ((size_t)s * N_R + r) * 64;
    float rw[64];
    const float4* rp = reinterpret_cast<const float4*>(act + base);
    #pragma unroll
    for (int i = 0; i < 16; i++) reinterpret_cast<float4*>(rw)[i] = rp[i];

    float m = mask[(size_t)s * N_R + r];

    float sum = 0.f, ss = 0.f;
    #pragma unroll
    for (int c = 0; c < 64; c++) { sum += rw[c]; ss += rw[c] * rw[c]; }
    float mu  = sum * (1.f / 64.f);
    float var = ss * (1.f / 64.f) - mu * mu;
    float rsd = rsqrtf(var + LN_EPS);

    float kacc[8], vacc[8];
    #pragma unroll
    for (int d = 0; d < 8; d++) { kacc[d] = 0.f; vacc[d] = 0.f; }

    #pragma unroll
    for (int c = 0; c < 64; c++) {
      float xn = fmaf((rw[c] - mu) * rsd, lns[c], lnb[c]);
      qacc[c] = fmaf(m, xn, qacc[c]);
      #pragma unroll
      for (int d = 0; d < 8; d++) {
        kacc[d] = fmaf(xn, kw[c * 8 + d], kacc[d]);
        vacc[d] = fmaf(xn, vw[c * 8 + d], vacc[d]);
      }
    }
    union { uint4 u; _Float16 h[8]; } kb, vb;
    #pragma unroll
    for (int d = 0; d < 8; d++) { kb.h[d] = (_Float16)kacc[d]; vb.h[d] = (_Float16)vacc[d]; }
    *reinterpret_cast<uint4*>(&sh.kv[s][0]) = kb.u;
    *reinterpret_cast<uint4*>(&sh.kv[s][8]) = vb.u;
    msum += m;
  }

  // block-reduce qacc + msum
  #pragma unroll
  for (int c = 0; c < 64; c++) {
    #pragma unroll
    for (int o = 32; o > 0; o >>= 1) qacc[c] += __shfl_xor(qacc[c], o);
  }
  #pragma unroll
  for (int o = 32; o > 0; o >>= 1) msum += __shfl_xor(msum, o);
  if (lane == 0) {
    redB[wave][0] = msum;
    #pragma unroll
    for (int c = 0; c < 64; c++) redA[wave][c] = qacc[c];
  }
  __syncthreads();
  if (tid < 64) {
    float qs = redA[0][tid] + redA[1][tid] + redA[2][tid] + redA[3][tid];
    float mt = redB[0][0] + redB[1][0] + redB[2][0] + redB[3][0];
    q_lds[tid] = qs / (mt + MEAN_EPS);
  }
  __syncthreads();
  if (tid < 64) {
    float acc = 0.f;
    for (int c = 0; c < 64; c++) acc = fmaf(q_lds[c], qw[c * 64 + tid], acc);
    qf_lds[tid] = acc * QSCALE;
  }
  __syncthreads();

  // ================= softmax over s (per head) + weighted_avg =================
  float qreg[64];
  #pragma unroll
  for (int j = 0; j < 64; j++) qreg[j] = qf_lds[j];

  float ev[4][8];
  float hm[8];
  #pragma unroll
  for (int h = 0; h < 8; h++) hm[h] = -1e30f;

  #pragma unroll
  for (int it = 0; it < 4; it++) {
    int s = tid + it * 256;
    union { uint4 u; _Float16 h[8]; } kb;
    kb.u = *reinterpret_cast<uint4*>(&sh.kv[s][0]);
    float kk[8];
    #pragma unroll
    for (int d = 0; d < 8; d++) kk[d] = (float)kb.h[d];
    float m = mask[(size_t)s * N_R + r];
    float bias = LARGE_F * (m - 1.f);
    #pragma unroll
    for (int h = 0; h < 8; h++) {
      float l = bias;
      #pragma unroll
      for (int d = 0; d < 8; d++) l = fmaf(qreg[h * 8 + d], kk[d], l);
      ev[it][h] = l;
      hm[h] = fmaxf(hm[h], l);
    }
  }
  #pragma unroll
  for (int h = 0; h < 8; h++) {
    #pragma unroll
    for (int o = 32; o > 0; o >>= 1) hm[h] = fmaxf(hm[h], __shfl_xor(hm[h], o));
  }
  if (lane == 0) {
    #pragma unroll
    for (int h = 0; h < 8; h++) redB[wave][h] = hm[h];
  }
  __syncthreads();
  #pragma unroll
  for (int h = 0; h < 8; h++)
    hm[h] = fmaxf(fmaxf(redB[0][h], redB[1][h]), fmaxf(redB[2][h], redB[3][h]));
  __syncthreads();  // done reading maxes; redB reused for sums

  float hs[8];
  #pragma unroll
  for (int h = 0; h < 8; h++) hs[h] = 0.f;
  #pragma unroll
  for (int it = 0; it < 4; it++) {
    #pragma unroll
    for (int h = 0; h < 8; h++) {
      float e = __expf(ev[it][h] - hm[h]);
      ev[it][h] = e;
      hs[h] += e;
    }
  }
  #pragma unroll
  for (int h = 0; h < 8; h++) {
    #pragma unroll
    for (int o = 32; o > 0; o >>= 1) hs[h] += __shfl_xor(hs[h], o);
  }
  if (lane == 0) {
    #pragma unroll
    for (int h = 0; h < 8; h++) redB[wave][h] = hs[h];
  }
  __syncthreads();

  float wacc[64];
  #pragma unroll
  for (int j = 0; j < 64; j++) wacc[j] = 0.f;
  #pragma unroll
  for (int it = 0; it < 4; it++) {
    int s = tid + it * 256;
    union { uint4 u; _Float16 h[8]; } vb;
    vb.u = *reinterpret_cast<uint4*>(&sh.kv[s][8]);
    float vv[8];
    #pragma unroll
    for (int d = 0; d < 8; d++) vv[d] = (float)vb.h[d];
    #pragma unroll
    for (int h = 0; h < 8; h++) {
      float w = ev[it][h];
      #pragma unroll
      for (int d = 0; d < 8; d++) wacc[h * 8 + d] = fmaf(w, vv[d], wacc[h * 8 + d]);
    }
  }
  #pragma unroll
  for (int j = 0; j < 64; j++) {
    #pragma unroll
    for (int o = 32; o > 0; o >>= 1) wacc[j] += __shfl_xor(wacc[j], o);
  }
  if (lane == 0) {
    #pragma unroll
    for (int j = 0; j < 64; j++) redA[wave][j] = wacc[j];
  }
  __syncthreads();
  if (tid < 64) {
    int h = tid >> 3;
    float hsv = redB[0][h] + redB[1][h] + redB[2][h] + redB[3][h];
    wavg_lds[tid] = (redA[0][tid] + redA[1][tid] + redA[2][tid] + redA[3][tid]) / hsv;
  }
  __syncthreads();  // also transitions LDS union: kv -> stage

  // ================= pass 2: LN again + gate + output projection =================
  #pragma unroll 1
  for (int it = 0; it < 4; it++) {
    int s = tid + it * 256;
    size_t base = ((size_t)s * N_R + r) * 64;
    float rw[64];
    const float4* rp = reinterpret_cast<const float4*>(act + base);
    #pragma unroll
    for (int i = 0; i < 16; i++) reinterpret_cast<float4*>(rw)[i] = rp[i];

    float sum = 0.f, ss = 0.f;
    #pragma unroll
    for (int c = 0; c < 64; c++) { sum += rw[c]; ss += rw[c] * rw[c]; }
    float mu  = sum * (1.f / 64.f);
    float rsd = rsqrtf(ss * (1.f / 64.f) - mu * mu + LN_EPS);

    unsigned* srow = sh.stage[tid];
    #pragma unroll
    for (int i = 0; i < 32; i++) {
      float xa = fmaf((rw[2 * i]     - mu) * rsd, lns[2 * i],     lnb[2 * i]);
      float xb = fmaf((rw[2 * i + 1] - mu) * rsd, lns[2 * i + 1], lnb[2 * i + 1]);
      srow[i] = (unsigned)f2b(xa) | ((unsigned)f2b(xb) << 16);
    }

    // gate accumulation: gacc[j] = sum_c xn[c] * gating_w[c][j]
    float gacc[64];
    #pragma unroll
    for (int j = 0; j < 64; j++) gacc[j] = 0.f;
    for (int c2 = 0; c2 < 32; c2++) {
      unsigned u = srow[c2];
      float xa = bflo(u), xb = bfhi(u);
      const float* wg0 = gw + (2 * c2) * 64;
      const float* wg1 = gw + (2 * c2 + 1) * 64;
      #pragma unroll
      for (int j = 0; j < 64; j++) gacc[j] = fmaf(xa, wg0[j], gacc[j]);
      #pragma unroll
      for (int j = 0; j < 64; j++) gacc[j] = fmaf(xb, wg1[j], gacc[j]);
    }
    // coef[j] = wavg[j] * sigmoid(gacc[j] + gating_b[j]) -> stage (bf16 pairs)
    #pragma unroll
    for (int j2 = 0; j2 < 32; j2++) {
      float t0 = gacc[2 * j2]     + gb[2 * j2];
      float t1 = gacc[2 * j2 + 1] + gb[2 * j2 + 1];
      float g0 = 1.f / (1.f + __expf(-t0));
      float g1 = 1.f / (1.f + __expf(-t1));
      float c0 = wavg_lds[2 * j2]     * g0;
      float c1 = wavg_lds[2 * j2 + 1] * g1;
      srow[j2] = (unsigned)f2b(c0) | ((unsigned)f2b(c1) << 16);
    }
    // output projection: oacc[c] = sum_j coef[j] * output_w[j][c]
    float oacc[64];
    #pragma unroll
    for (int c = 0; c < 64; c++) oacc[c] = 0.f;
    for (int j2 = 0; j2 < 32; j2++) {
      unsigned u = srow[j2];
      float c0 = bflo(u), c1 = bfhi(u);
      const float* wo0 = ow + (2 * j2) * 64;
      const float* wo1 = ow + (2 * j2 + 1) * 64;
      #pragma unroll
      for (int c = 0; c < 64; c++) oacc[c] = fmaf(c0, wo0[c], oacc[c]);
      #pragma unroll
      for (int c = 0; c < 64; c++) oacc[c] = fmaf(c1, wo1[c], oacc[c]);
    }
    float4* op = reinterpret_cast<float4*>(out + base);
    #pragma unroll
    for (int i = 0; i < 16; i++) {
      float4 v4;
      v4.x = oacc[4 * i]     + ob[4 * i];
      v4.y = oacc[4 * i + 1] + ob[4 * i + 1];
      v4.z = oacc[4 * i + 2] + ob[4 * i + 2];
      v4.w = oacc[4 * i + 3] + ob[4 * i + 3];
      op[i] = v4;
    }
  }
}

extern "C" void kernel_launch(void* const* d_in, const int* in_sizes, int n_in,
                              void* d_out, int out_size, void* d_ws, size_t ws_size,
                              hipStream_t stream)
{
  const float* act  = (const float*)d_in[0];
  const float* mask = (const float*)d_in[1];
  const float* lns  = (const float*)d_in[2];
  const float* lnb  = (const float*)d_in[3];
  const float* qw   = (const float*)d_in[4];
  const float* kw   = (const float*)d_in[5];
  const float* vw   = (const float*)d_in[6];
  const float* gw   = (const float*)d_in[7];
  const float* gb   = (const float*)d_in[8];
  const float* ow   = (const float*)d_in[9];
  const float* ob   = (const float*)d_in[10];

  attn_kernel<<<N_R, 256, 0, stream>>>(act, mask, lns, lnb, qw, kw, vw,
                                       gw, gb, ow, ob, (float*)d_out);
}